// Round 3
// baseline (778.184 us; speedup 1.0000x reference)
//
#include <hip/hip_runtime.h>
#include <math.h>

typedef unsigned short ush;
typedef float v4f __attribute__((ext_vector_type(4)));

#define EPSc 1e-6f

// ---- problem constants (B=1024, D=1024, N=256, WD=64, R=4, NW=1) ----
#define NB 1024
#define ND 1024
#define NN 256
#define NWD 64
#define NR 4

// output element offsets (concat of return tuple, fp32)
#define OFF_RWORDS   ((size_t)0)
#define OFF_MEM      ((size_t)262144)
#define OFF_RWEIGHTS ((size_t)17039360)
#define OFF_WW       ((size_t)18087936)
#define OFF_LINK     ((size_t)18350080)
#define OFF_PREC     ((size_t)85458944)
#define OFF_USAGE    ((size_t)85721088)

// workspace float offsets
#define WS_PART   ((size_t)0)          // 4*1024*512 = 2M floats; reused by k4 for bw partials
#define WS_PARAMS ((size_t)2097152)    // 1024*672
#define WS_FW     ((size_t)2785280)    // 1024*4*256
// per-batch param block layout (stride 672):
//   wv[64]@0, er[64]@64, rk[256]@128, rs[4]@384, mode[12]@388 (r*3 + {bwd,fwd,cnt}), ww[256]@400

struct Ptrs {
  const float* W[10];
  const float* Bv[10];
};

__device__ __forceinline__ float b2f(ush h){
  union { unsigned int u; float f; } v; v.u = ((unsigned int)h) << 16; return v.f;
}
__device__ __forceinline__ ush f2b(float f){
  union { float f; unsigned int u; } v; v.f = f;
  unsigned int u = v.u;
  u += 0x7fffu + ((u >> 16) & 1u);
  return (ush)(u >> 16);
}
__device__ __forceinline__ float u16lo(unsigned int w){
  union { unsigned int u; float f; } v; v.u = w << 16; return v.f;
}
__device__ __forceinline__ float u16hi(unsigned int w){
  union { unsigned int u; float f; } v; v.u = w & 0xffff0000u; return v.f;
}
__device__ __forceinline__ float sigm(float x){ return 1.f/(1.f+expf(-x)); }
__device__ __forceinline__ float softplus(float x){ return fmaxf(x,0.f) + log1pf(expf(-fabsf(x))); }

// col -> (matrix, local col, out-dim); packed order: wv,ev,fg,ag,wg,rm,ws,rs,wk,rk
__device__ __forceinline__ int colmap(int c, int& lc, int& od){
  const int starts[11] = {0,64,128,132,133,134,146,147,151,215,471};
  const int ods[10]    = {64,64,4,1,1,12,1,4,64,256};
  int m = 0;
  #pragma unroll
  for (int i=1;i<10;i++) if (c >= starts[i]) m = i;
  lc = c - starts[m]; od = ods[m];
  return m;
}

// ---------------- K1: projection GEMM, split-K partials ----------------
// grid (128 batch-tiles, 4 k-chunks), 256 threads; 2 output columns per thread,
// 8 batch rows per block. Ctrl read directly from global with BLOCK-UNIFORM
// addresses (compiler scalarizes to s_load; no LDS, no barriers).
__global__ __launch_bounds__(256) void k1_gemm(const float* __restrict__ ctrl, Ptrs P,
                                               float* __restrict__ part){
  int bt = blockIdx.x;      // 8 batch rows
  int kc = blockIdx.y;      // 256-wide D chunk
  int t  = threadIdx.x;
  int c0 = t;
  bool has1 = (t + 256 < 471);
  int c1 = has1 ? t + 256 : 470;
  int lc0, od0, lc1, od1;
  int m0 = colmap(c0, lc0, od0);
  int m1 = colmap(c1, lc1, od1);
  const float* w0p = P.W[m0] + lc0;
  const float* w1p = P.W[m1] + lc1;
  float acc0[8], acc1[8];
  #pragma unroll
  for (int r=0;r<8;r++){ acc0[r]=0.f; acc1[r]=0.f; }
  const float* cb = ctrl + (size_t)(bt*8)*ND + kc*256;
  for (int d0 = 0; d0 < 256; d0 += 4){
    float4 cv[8];
    #pragma unroll
    for (int r=0;r<8;r++) cv[r] = *(const float4*)(cb + (size_t)r*ND + d0);
    #pragma unroll
    for (int k=0;k<4;k++){
      size_t dg = (size_t)(kc*256 + d0 + k);
      float wv0 = w0p[dg*od0];
      float wv1 = w1p[dg*od1];
      #pragma unroll
      for (int r=0;r<8;r++){
        float cvk = ((const float*)&cv[r])[k];
        acc0[r] += cvk*wv0;
        acc1[r] += cvk*wv1;
      }
    }
  }
  #pragma unroll
  for (int r=0;r<8;r++)
    part[((size_t)kc*NB + bt*8+r)*512 + c0] = acc0[r];
  if (has1){
    #pragma unroll
    for (int r=0;r<8;r++)
      part[((size_t)kc*NB + bt*8+r)*512 + c1] = acc1[r];
  }
}

// ---------------- K2: gates, usage, allocation (sort), write content/weights, precedence ----
// grid 1024 (batch), 256 threads. Wave-level shuffles for sort/scan/reductions.

// in-wave bitonic stage (j<=32): partner via shfl, no barrier
#define SSTAGE(j,k) { \
  float kp = __shfl_xor(key, (j)); int ip = __shfl_xor(idx, (j)); \
  bool gt = (key > kp) || (key == kp && idx > ip); \
  bool selmin = (((t & (k)) == 0) == ((t & (j)) == 0)); \
  if (selmin == gt){ key = kp; idx = ip; } }

// cross-wave bitonic stage (j>=64): LDS exchange
#define LSTAGE(j,k) { \
  sk[t] = key; si[t] = idx; __syncthreads(); \
  float kp = sk[t^(j)]; int ip = si[t^(j)]; \
  bool gt = (key > kp) || (key == kp && idx > ip); \
  bool selmin = (((t & (k)) == 0) == ((t & (j)) == 0)); \
  if (selmin == gt){ key = kp; idx = ip; } \
  __syncthreads(); }

__global__ __launch_bounds__(256) void k2_gates(
    const float* __restrict__ part, Ptrs P,
    const float* __restrict__ mem, const float* __restrict__ prw_in,
    const float* __restrict__ pww_in, const float* __restrict__ pprec,
    const float* __restrict__ pusage,
    float* __restrict__ params,
    float* __restrict__ out_ww, float* __restrict__ out_prec, float* __restrict__ out_usage)
{
  int b = blockIdx.x, t = threadIdx.x;
  int w = t >> 6, l = t & 63;
  __shared__ float proj[512];
  __shared__ float wkL[64];
  __shared__ float scal[12]; // fg[4]@0, ag@4, wg@5, wstr@6, kn@7
  __shared__ float wred[16]; // [0..3] max, [4..7] sum, [8..11] scan totals, [12..15] wsum
  __shared__ float sk[256];
  __shared__ int   si[256];
  __shared__ float salloc[256];

  // 1. reduce split-K partials + bias
  for (int c = t; c < 471; c += 256){
    float v = 0.f;
    #pragma unroll
    for (int kc=0;kc<4;kc++) v += part[((size_t)kc*NB + b)*512 + c];
    int lc, od; int m = colmap(c, lc, od);
    v += P.Bv[m][lc];
    proj[c] = v;
  }
  __syncthreads();

  // 2. activations -> param block / LDS scalars
  float* pb = params + (size_t)b*672;
  if (t < 64){
    pb[t] = proj[t];              // write vector (raw)
    pb[64+t] = sigm(proj[64+t]);  // erase vector
    wkL[t] = proj[151+t];         // write key
  }
  pb[128 + t] = proj[215 + t];    // read keys (raw), 256
  if (t < 4){
    pb[384 + t] = softplus(proj[147 + t]);  // read strengths
    // read mode softmax over 3 (order: backward, forward, content)
    float a = proj[134 + 3*t], bq = proj[134 + 3*t + 1], c2 = proj[134 + 3*t + 2];
    float mx = fmaxf(a, fmaxf(bq, c2));
    float ea = expf(a-mx), eb = expf(bq-mx), ec = expf(c2-mx);
    float s = ea+eb+ec;
    pb[388 + 3*t]     = ea/s;
    pb[388 + 3*t + 1] = eb/s;
    pb[388 + 3*t + 2] = ec/s;
    scal[t] = sigm(proj[128+t]); // free gate
  }
  if (t == 0){
    scal[4] = sigm(proj[132]);      // allocation gate
    scal[5] = sigm(proj[133]);      // write gate
    scal[6] = softplus(proj[146]);  // write strength
  }
  if (w == 0){
    float kv = proj[151 + l];
    float s2 = kv*kv;
    #pragma unroll
    for (int off=32; off>0; off>>=1) s2 += __shfl_xor(s2, off);
    if (l == 0) scal[7] = sqrtf(s2); // ||write key||
  }
  __syncthreads();

  // 3. usage
  float us;
  {
    float pu = pusage[(size_t)b*NN + t];
    float pw = pww_in[(size_t)b*NN + t];
    float uaw = pu + (1.f-pu)*pw;
    float phi = 1.f;
    #pragma unroll
    for (int r=0;r<4;r++)
      phi *= (1.f - scal[r]*prw_in[((size_t)b*NR + r)*NN + t]);
    us = uaw*phi;
    out_usage[(size_t)b*NN + t] = us;
  }

  // 4. write content: cosine similarity vs old memory, softmax over n (wave reductions)
  float sim;
  {
    const float* mrow = mem + ((size_t)b*NN + t)*NWD;
    float dot = 0.f, n2 = 0.f;
    for (int d0=0; d0<64; d0+=4){
      float4 q = *(const float4*)(mrow + d0);
      dot += wkL[d0]*q.x + wkL[d0+1]*q.y + wkL[d0+2]*q.z + wkL[d0+3]*q.w;
      n2  += q.x*q.x + q.y*q.y + q.z*q.z + q.w*q.w;
    }
    sim = scal[6]*dot/(scal[7]*sqrtf(n2) + EPSc);
  }
  {
    float m_ = sim;
    #pragma unroll
    for (int off=32; off>0; off>>=1) m_ = fmaxf(m_, __shfl_xor(m_, off));
    if (l == 0) wred[w] = m_;
  }
  __syncthreads();
  float mx = fmaxf(fmaxf(wred[0],wred[1]), fmaxf(wred[2],wred[3]));
  float e = expf(sim - mx);
  {
    float s_ = e;
    #pragma unroll
    for (int off=32; off>0; off>>=1) s_ += __shfl_xor(s_, off);
    if (l == 0) wred[4+w] = s_;
  }
  __syncthreads();
  float content = e / (wred[4]+wred[5]+wred[6]+wred[7]);

  // 5. allocation: bitonic sort (in-wave shuffles; LDS only for j>=64), shuffle scan
  float key = EPSc + (1.f-EPSc)*us;
  int idx = t;
  SSTAGE(1,2)
  SSTAGE(2,4)  SSTAGE(1,4)
  SSTAGE(4,8)  SSTAGE(2,8)  SSTAGE(1,8)
  SSTAGE(8,16) SSTAGE(4,16) SSTAGE(2,16) SSTAGE(1,16)
  SSTAGE(16,32) SSTAGE(8,32) SSTAGE(4,32) SSTAGE(2,32) SSTAGE(1,32)
  SSTAGE(32,64) SSTAGE(16,64) SSTAGE(8,64) SSTAGE(4,64) SSTAGE(2,64) SSTAGE(1,64)
  LSTAGE(64,128)
  SSTAGE(32,128) SSTAGE(16,128) SSTAGE(8,128) SSTAGE(4,128) SSTAGE(2,128) SSTAGE(1,128)
  LSTAGE(128,256)
  LSTAGE(64,256)
  SSTAGE(32,256) SSTAGE(16,256) SSTAGE(8,256) SSTAGE(4,256) SSTAGE(2,256) SSTAGE(1,256)

  // inclusive cumprod: in-wave shuffle scan + cross-wave totals
  float v = key;
  #pragma unroll
  for (int off=1; off<64; off<<=1){
    float u = __shfl_up(v, off);
    if (l >= off) v *= u;
  }
  if (l == 63) wred[8+w] = v;
  __syncthreads();
  float pre = 1.f;
  #pragma unroll
  for (int q=0; q<3; q++) if (q < w) pre *= wred[8+q];
  float exv = __shfl_up(v, 1);
  if (l == 0) exv = 1.f;
  float excl = exv * pre;
  float s_alloc = (1.f - key) * excl;
  salloc[idx] = s_alloc;   // scatter back to original index
  __syncthreads();
  float alloc = salloc[t];

  // 6. write weights + precedence
  float ag = scal[4], wg = scal[5];
  float ww = wg*(ag*alloc + (1.f-ag)*content);
  pb[400 + t] = ww;
  out_ww[(size_t)b*NN + t] = ww;
  {
    float s_ = ww;
    #pragma unroll
    for (int off=32; off>0; off>>=1) s_ += __shfl_xor(s_, off);
    if (l == 0) wred[12+w] = s_;
  }
  __syncthreads();
  float wsum = wred[12]+wred[13]+wred[14]+wred[15];
  float prec = (1.f - wsum)*pprec[(size_t)b*NN + t] + ww;
  out_prec[(size_t)b*NN + t] = prec;
}

// ---------------- K4: fused link update + forward/backward matvecs (streaming) ----------------
// grid (1024 batch, 2 row-chunks), 256 threads. float4 stream of plink/out_link.
__global__ __launch_bounds__(256) void k4_link(
    const float* __restrict__ plink, const float* __restrict__ pprec,
    const float* __restrict__ prw_in, const float* __restrict__ params,
    float* __restrict__ out_link, float* __restrict__ fw, float* __restrict__ bwp)
{
  int b = blockIdx.x, cc = blockIdx.y, t = threadIdx.x;
  int w = t >> 6, l = t & 63;
  __shared__ float wwl[256], ppl[256], prwl[4*256];
  __shared__ v4f   bred[4][4][64];   // [wave][r][lane] -> 4 cols, 16 KB
  __shared__ float fwbuf[4*128];     // [wave][r*32+k]
  const float* pb = params + (size_t)b*672;
  wwl[t] = pb[400 + t];
  ppl[t] = pprec[(size_t)b*NN + t];
  #pragma unroll
  for (int r=0;r<4;r++) prwl[r*256 + t] = prw_in[((size_t)b*NR + r)*NN + t];
  __syncthreads();

  // per-lane column-constant registers (cols 4l..4l+3)
  v4f wwj = *(const v4f*)&wwl[4*l];
  v4f ppj = *(const v4f*)&ppl[4*l];
  v4f pr0 = *(const v4f*)&prwl[0*256 + 4*l];
  v4f pr1 = *(const v4f*)&prwl[1*256 + 4*l];
  v4f pr2 = *(const v4f*)&prwl[2*256 + 4*l];
  v4f pr3 = *(const v4f*)&prwl[3*256 + 4*l];

  v4f bacc0 = {0.f,0.f,0.f,0.f}, bacc1 = bacc0, bacc2 = bacc0, bacc3 = bacc0;

  int i0 = cc*128 + w*32;                      // this wave's 32-row strip
  const v4f* plrow = (const v4f*)(plink + ((size_t)b*NN + i0)*NN) + l;
  float*     olbase = out_link + ((size_t)b*NN + i0)*NN + 4*l;

  #pragma unroll 2
  for (int k=0; k<32; k++){
    int i = i0 + k;
    v4f pl = plrow[(size_t)k*64];
    float wwi = wwl[i];                         // wave-uniform LDS broadcasts
    float c1  = 1.f - wwi;
    float pi0 = prwl[0*256+i], pi1 = prwl[1*256+i],
          pi2 = prwl[2*256+i], pi3 = prwl[3*256+i];
    v4f lv = (c1 - wwj)*pl + wwi*ppj;
    if (l == (i>>2)) lv[i&3] = 0.f;             // zero diagonal before matvecs
    __builtin_nontemporal_store(lv, (v4f*)(olbase + (size_t)k*NN));

    // forward partials (reduce over j within wave) + backward accumulators
    v4f f0 = pr0*lv, f1 = pr1*lv, f2 = pr2*lv, f3 = pr3*lv;
    float s0 = f0.x+f0.y+f0.z+f0.w;
    float s1 = f1.x+f1.y+f1.z+f1.w;
    float s2 = f2.x+f2.y+f2.z+f2.w;
    float s3 = f3.x+f3.y+f3.z+f3.w;
    bacc0 += pi0*lv; bacc1 += pi1*lv; bacc2 += pi2*lv; bacc3 += pi3*lv;

    // packed butterfly: 2 steps on all four, select by lane&3, 4 more steps
    s0 += __shfl_xor(s0,1); s0 += __shfl_xor(s0,2);
    s1 += __shfl_xor(s1,1); s1 += __shfl_xor(s1,2);
    s2 += __shfl_xor(s2,1); s2 += __shfl_xor(s2,2);
    s3 += __shfl_xor(s3,1); s3 += __shfl_xor(s3,2);
    float v = (l&1) ? ((l&2)? s3 : s1) : ((l&2)? s2 : s0);
    v += __shfl_xor(v,4); v += __shfl_xor(v,8);
    v += __shfl_xor(v,16); v += __shfl_xor(v,32);
    if (l < 4) fwbuf[w*128 + l*32 + k] = v;     // lane r holds fw[r][i]
  }

  bred[w][0][l] = bacc0;
  bred[w][1][l] = bacc1;
  bred[w][2][l] = bacc2;
  bred[w][3][l] = bacc3;
  __syncthreads();

  // combine backward across waves -> chunk partial; write fw coalesced
  {
    int r = t >> 6, l2 = t & 63;
    v4f a = bred[0][r][l2], b4 = bred[1][r][l2],
        c4 = bred[2][r][l2], d4 = bred[3][r][l2];
    v4f s = a + b4 + c4 + d4;
    *(v4f*)&bwp[(((size_t)cc*NB + b)*NR + r)*NN + 4*l2] = s;
    #pragma unroll
    for (int e=0;e<2;e++){
      int idx = t + e*256;
      int rr = idx >> 7, j = idx & 127;
      fw[((size_t)b*NR + rr)*NN + cc*128 + j] = fwbuf[(j>>5)*128 + rr*32 + (j&31)];
    }
  }
}

// ---------------- K5: memory update, read content/weights/words ----------------
// grid 1024 (batch), 256 threads. bf16 new-memory copy stored d-major
// (memt[d*264+n]) so phase 4 reads 8 bf16 per ds_read_b128.
#define MSTR 264
__global__ __launch_bounds__(256) void k5_read(
    const float* __restrict__ mem, const float* __restrict__ params,
    const float* __restrict__ fw, const float* __restrict__ bwp,
    float* __restrict__ out_rwords, float* __restrict__ out_mem, float* __restrict__ out_rweights)
{
  int b = blockIdx.x, t = threadIdx.x;
  __shared__ ush   memt[64*MSTR];  // d-major bf16 new memory, 33 KB
  __shared__ float wvl[64], erl[64], rkl[256];
  __shared__ float siml[4*260];
  __shared__ float rwl[4*260];
  __shared__ float scal[32]; // kn[4]@0, M[4]@4, S[4]@8, rs[4]@12, mode[12]@16
  const float* pb = params + (size_t)b*672;
  if (t < 64){ wvl[t] = pb[t]; erl[t] = pb[64+t]; }
  rkl[t] = pb[128 + t];
  if (t < 4)  scal[12+t] = pb[384+t];
  if (t < 12) scal[16+t] = pb[388+t];
  __syncthreads();
  if (t < 4){
    float s = 0.f;
    for (int d=0;d<64;d++){ float v = rkl[t*64+d]; s += v*v; }
    scal[t] = sqrtf(s);
  }
  __syncthreads();

  // phase 1: memory erase/write; dots with read keys; row norms
  float wwn = pb[400 + t];
  const float* mrow = mem + ((size_t)b*NN + t)*NWD;
  float* orow = out_mem + ((size_t)b*NN + t)*NWD;
  float n2=0.f, dot0=0.f, dot1=0.f, dot2=0.f, dot3=0.f;
  for (int d0=0; d0<64; d0+=4){
    float4 q = *(const float4*)(mrow + d0);
    float4 qo;
    float* qi = (float*)&q;
    float* po = (float*)&qo;
    #pragma unroll
    for (int k=0;k<4;k++){
      int d = d0+k;
      float m = qi[k];
      float nv = m*(1.f - wwn*erl[d]) + wwn*wvl[d];
      po[k] = nv;
      n2 += nv*nv;
      dot0 += rkl[0*64+d]*nv;
      dot1 += rkl[1*64+d]*nv;
      dot2 += rkl[2*64+d]*nv;
      dot3 += rkl[3*64+d]*nv;
      memt[d*MSTR + t] = f2b(nv);   // d-major store; lanes n consecutive -> conflict-free
    }
    *(float4*)(orow + d0) = qo;
  }
  float sn = sqrtf(n2);
  siml[0*260+t] = scal[12]*dot0/(scal[0]*sn + EPSc);
  siml[1*260+t] = scal[13]*dot1/(scal[1]*sn + EPSc);
  siml[2*260+t] = scal[14]*dot2/(scal[2]*sn + EPSc);
  siml[3*260+t] = scal[15]*dot3/(scal[3]*sn + EPSc);
  __syncthreads();

  // phase 2: softmax over n per r (wave rr handles r=rr)
  int rr = t >> 6, lane = t & 63;
  {
    float m1 = -1e30f;
    #pragma unroll
    for (int q2=0;q2<4;q2++) m1 = fmaxf(m1, siml[rr*260 + q2*64 + lane]);
    #pragma unroll
    for (int off=32; off>0; off>>=1) m1 = fmaxf(m1, __shfl_xor(m1, off));
    float s1 = 0.f;
    #pragma unroll
    for (int q2=0;q2<4;q2++) s1 += expf(siml[rr*260 + q2*64 + lane] - m1);
    #pragma unroll
    for (int off=32; off>0; off>>=1) s1 += __shfl_xor(s1, off);
    if (lane == 0){ scal[4+rr] = m1; scal[8+rr] = s1; }
  }
  __syncthreads();

  // phase 3: read weights = cm*content + fm*forward + bm*backward (bw = sum of 2 chunk partials)
  #pragma unroll
  for (int r=0;r<4;r++){
    float c = expf(siml[r*260+t] - scal[4+r]) / scal[8+r];
    float fwv = fw[((size_t)b*NR + r)*NN + t];
    float bwv = bwp[((size_t)b*NR + r)*NN + t]
              + bwp[((size_t)(NB + b)*NR + r)*NN + t];
    float rwv = scal[16+3*r+2]*c + scal[16+3*r+1]*fwv + scal[16+3*r+0]*bwv;
    rwl[r*260 + t] = rwv;
    out_rweights[((size_t)b*NR + r)*NN + t] = rwv;
  }
  __syncthreads();

  // phase 4: read words = rw @ new memory (wave rr, lane = d); 8 bf16 per b128
  {
    float acc = 0.f;
    const ush* mcol = &memt[lane*MSTR];
    const float* rrow = &rwl[rr*260];
    #pragma unroll 4
    for (int q=0; q<32; q++){
      uint4  u  = *(const uint4*)(mcol + 8*q);
      float4 ra = *(const float4*)(rrow + 8*q);
      float4 rb = *(const float4*)(rrow + 8*q + 4);
      acc += ra.x*u16lo(u.x) + ra.y*u16hi(u.x)
           + ra.z*u16lo(u.y) + ra.w*u16hi(u.y)
           + rb.x*u16lo(u.z) + rb.y*u16hi(u.z)
           + rb.z*u16lo(u.w) + rb.w*u16hi(u.w);
    }
    out_rwords[((size_t)b*NR + rr)*NWD + lane] = acc;
  }
}

extern "C" void kernel_launch(void* const* d_in, const int* in_sizes, int n_in,
                              void* d_out, int out_size, void* d_ws, size_t ws_size,
                              hipStream_t stream) {
  const float* ctrl   = (const float*)d_in[0];
  const float* mem    = (const float*)d_in[1];
  const float* prw    = (const float*)d_in[2];
  const float* pww    = (const float*)d_in[3];
  const float* plink  = (const float*)d_in[4];
  const float* pprec  = (const float*)d_in[5];
  const float* pusage = (const float*)d_in[6];
  Ptrs P;
  for (int i=0;i<10;i++){
    P.W[i]  = (const float*)d_in[7 + 2*i];
    P.Bv[i] = (const float*)d_in[8 + 2*i];
  }
  float* ws = (float*)d_ws;
  float* part   = ws + WS_PART;
  float* params = ws + WS_PARAMS;
  float* fw     = ws + WS_FW;

  float* o = (float*)d_out;
  float* out_rwords   = o + OFF_RWORDS;
  float* out_mem      = o + OFF_MEM;
  float* out_rweights = o + OFF_RWEIGHTS;
  float* out_ww       = o + OFF_WW;
  float* out_link     = o + OFF_LINK;
  float* out_prec     = o + OFF_PREC;
  float* out_usage    = o + OFF_USAGE;

  k1_gemm<<<dim3(128,4), 256, 0, stream>>>(ctrl, P, part);
  k2_gates<<<NB, 256, 0, stream>>>(part, P, mem, prw, pww, pprec, pusage,
                                   params, out_ww, out_prec, out_usage);
  // k4 reuses `part` (k2 is done with it) for backward chunk partials: 2*1024*4*256 floats
  k4_link<<<dim3(NB,2), 256, 0, stream>>>(plink, pprec, prw, params, out_link, fw, part);
  k5_read<<<NB, 256, 0, stream>>>(mem, params, fw, part,
                                  out_rwords, out_mem, out_rweights);
}

// Round 4
// 734.928 us; speedup vs baseline: 1.0589x; 1.0589x over previous
//
#include <hip/hip_runtime.h>
#include <math.h>

typedef unsigned short ush;
typedef float v4f __attribute__((ext_vector_type(4)));

#define EPSc 1e-6f

// ---- problem constants (B=1024, D=1024, N=256, WD=64, R=4, NW=1) ----
#define NB 1024
#define ND 1024
#define NN 256
#define NWD 64
#define NR 4

// output element offsets (concat of return tuple, fp32)
#define OFF_RWORDS   ((size_t)0)
#define OFF_MEM      ((size_t)262144)
#define OFF_RWEIGHTS ((size_t)17039360)
#define OFF_WW       ((size_t)18087936)
#define OFF_LINK     ((size_t)18350080)
#define OFF_PREC     ((size_t)85458944)
#define OFF_USAGE    ((size_t)85721088)

// workspace float offsets
#define WS_PART   ((size_t)0)          // 4*1024*512 = 2M floats; reused by k4 for bw partials
#define WS_PARAMS ((size_t)2097152)    // 1024*672
#define WS_FW     ((size_t)2785280)    // 1024*4*256
// per-batch param block layout (stride 672):
//   wv[64]@0, er[64]@64, rk[256]@128, rs[4]@384, mode[12]@388 (r*3 + {bwd,fwd,cnt}), ww[256]@400

struct Ptrs {
  const float* W[10];
  const float* Bv[10];
};

__device__ __forceinline__ float b2f(ush h){
  union { unsigned int u; float f; } v; v.u = ((unsigned int)h) << 16; return v.f;
}
__device__ __forceinline__ ush f2b(float f){
  union { float f; unsigned int u; } v; v.f = f;
  unsigned int u = v.u;
  u += 0x7fffu + ((u >> 16) & 1u);
  return (ush)(u >> 16);
}
__device__ __forceinline__ float sigm(float x){ return 1.f/(1.f+expf(-x)); }
__device__ __forceinline__ float softplus(float x){ return fmaxf(x,0.f) + log1pf(expf(-fabsf(x))); }

// col -> (matrix, local col, out-dim); packed order: wv,ev,fg,ag,wg,rm,ws,rs,wk,rk
__device__ __forceinline__ int colmap(int c, int& lc, int& od){
  const int starts[11] = {0,64,128,132,133,134,146,147,151,215,471};
  const int ods[10]    = {64,64,4,1,1,12,1,4,64,256};
  int m = 0;
  #pragma unroll
  for (int i=1;i<10;i++) if (c >= starts[i]) m = i;
  lc = c - starts[m]; od = ods[m];
  return m;
}

// ---------------- K1: projection GEMM, split-K partials ----------------
// grid (128 batch-tiles, 4 k-chunks), 256 threads; 2 output columns per thread,
// 8 batch rows per block. Ctrl staged in LDS (stride 264 => aligned float4),
// read back as block-uniform ds_read_b128 broadcasts: 512 LDS instrs/wave
// (was 2048 scalar b32), 8 FMAs per b128.
__global__ __launch_bounds__(256) void k1_gemm(const float* __restrict__ ctrl, Ptrs P,
                                               float* __restrict__ part){
  int bt = blockIdx.x;      // 8 batch rows
  int kc = blockIdx.y;      // 256-wide D chunk
  int t  = threadIdx.x;
  __shared__ float cl[8*264];
  #pragma unroll
  for (int e=0;e<2;e++){
    int v = t + e*256;      // 512 float4 total
    int row = v >> 6, chunk = v & 63;
    const float* src = ctrl + (size_t)(bt*8+row)*ND + kc*256 + chunk*4;
    *(float4*)&cl[row*264 + chunk*4] = *(const float4*)src;
  }
  __syncthreads();
  int c0 = t;
  bool has1 = (t + 256 < 471);
  int c1 = has1 ? t + 256 : 470;
  int lc0, od0, lc1, od1;
  int m0 = colmap(c0, lc0, od0);
  int m1 = colmap(c1, lc1, od1);
  const float* w0p = P.W[m0] + lc0;
  const float* w1p = P.W[m1] + lc1;
  float acc0[8], acc1[8];
  #pragma unroll
  for (int r=0;r<8;r++){ acc0[r]=0.f; acc1[r]=0.f; }
  for (int d0 = 0; d0 < 256; d0 += 4){
    float4 cr[8];
    #pragma unroll
    for (int r=0;r<8;r++) cr[r] = *(const float4*)&cl[r*264 + d0];  // uniform b128 broadcast
    #pragma unroll
    for (int k=0;k<4;k++){
      size_t dg = (size_t)(kc*256 + d0 + k);
      float wv0 = w0p[dg*od0];
      float wv1 = w1p[dg*od1];
      #pragma unroll
      for (int r=0;r<8;r++){
        float cvk = ((const float*)&cr[r])[k];
        acc0[r] += cvk*wv0;
        acc1[r] += cvk*wv1;
      }
    }
  }
  #pragma unroll
  for (int r=0;r<8;r++)
    part[((size_t)kc*NB + bt*8+r)*512 + c0] = acc0[r];
  if (has1){
    #pragma unroll
    for (int r=0;r<8;r++)
      part[((size_t)kc*NB + bt*8+r)*512 + c1] = acc1[r];
  }
}

// ---------------- K2: gates, usage, allocation (sort), write content/weights, precedence ----
// grid 1024 (batch), 256 threads. Wave-level shuffles for sort/scan/reductions.

// in-wave bitonic stage (j<=32): partner via shfl, no barrier
#define SSTAGE(j,k) { \
  float kp = __shfl_xor(key, (j)); int ip = __shfl_xor(idx, (j)); \
  bool gt = (key > kp) || (key == kp && idx > ip); \
  bool selmin = (((t & (k)) == 0) == ((t & (j)) == 0)); \
  if (selmin == gt){ key = kp; idx = ip; } }

// cross-wave bitonic stage (j>=64): LDS exchange
#define LSTAGE(j,k) { \
  sk[t] = key; si[t] = idx; __syncthreads(); \
  float kp = sk[t^(j)]; int ip = si[t^(j)]; \
  bool gt = (key > kp) || (key == kp && idx > ip); \
  bool selmin = (((t & (k)) == 0) == ((t & (j)) == 0)); \
  if (selmin == gt){ key = kp; idx = ip; } \
  __syncthreads(); }

__global__ __launch_bounds__(256) void k2_gates(
    const float* __restrict__ part, Ptrs P,
    const float* __restrict__ mem, const float* __restrict__ prw_in,
    const float* __restrict__ pww_in, const float* __restrict__ pprec,
    const float* __restrict__ pusage,
    float* __restrict__ params,
    float* __restrict__ out_ww, float* __restrict__ out_prec, float* __restrict__ out_usage)
{
  int b = blockIdx.x, t = threadIdx.x;
  int w = t >> 6, l = t & 63;
  __shared__ float proj[512];
  __shared__ float wkL[64];
  __shared__ float scal[12]; // fg[4]@0, ag@4, wg@5, wstr@6, kn@7
  __shared__ float wred[16]; // [0..3] max, [4..7] sum, [8..11] scan totals, [12..15] wsum
  __shared__ float sk[256];
  __shared__ int   si[256];
  __shared__ float salloc[256];

  // 1. reduce split-K partials + bias
  for (int c = t; c < 471; c += 256){
    float v = 0.f;
    #pragma unroll
    for (int kc=0;kc<4;kc++) v += part[((size_t)kc*NB + b)*512 + c];
    int lc, od; int m = colmap(c, lc, od);
    v += P.Bv[m][lc];
    proj[c] = v;
  }
  __syncthreads();

  // 2. activations -> param block / LDS scalars
  float* pb = params + (size_t)b*672;
  if (t < 64){
    pb[t] = proj[t];              // write vector (raw)
    pb[64+t] = sigm(proj[64+t]);  // erase vector
    wkL[t] = proj[151+t];         // write key
  }
  pb[128 + t] = proj[215 + t];    // read keys (raw), 256
  if (t < 4){
    pb[384 + t] = softplus(proj[147 + t]);  // read strengths
    // read mode softmax over 3 (order: backward, forward, content)
    float a = proj[134 + 3*t], bq = proj[134 + 3*t + 1], c2 = proj[134 + 3*t + 2];
    float mx = fmaxf(a, fmaxf(bq, c2));
    float ea = expf(a-mx), eb = expf(bq-mx), ec = expf(c2-mx);
    float s = ea+eb+ec;
    pb[388 + 3*t]     = ea/s;
    pb[388 + 3*t + 1] = eb/s;
    pb[388 + 3*t + 2] = ec/s;
    scal[t] = sigm(proj[128+t]); // free gate
  }
  if (t == 0){
    scal[4] = sigm(proj[132]);      // allocation gate
    scal[5] = sigm(proj[133]);      // write gate
    scal[6] = softplus(proj[146]);  // write strength
  }
  if (w == 0){
    float kv = proj[151 + l];
    float s2 = kv*kv;
    #pragma unroll
    for (int off=32; off>0; off>>=1) s2 += __shfl_xor(s2, off);
    if (l == 0) scal[7] = sqrtf(s2); // ||write key||
  }
  __syncthreads();

  // 3. usage
  float us;
  {
    float pu = pusage[(size_t)b*NN + t];
    float pw = pww_in[(size_t)b*NN + t];
    float uaw = pu + (1.f-pu)*pw;
    float phi = 1.f;
    #pragma unroll
    for (int r=0;r<4;r++)
      phi *= (1.f - scal[r]*prw_in[((size_t)b*NR + r)*NN + t]);
    us = uaw*phi;
    out_usage[(size_t)b*NN + t] = us;
  }

  // 4. write content: cosine similarity vs old memory, softmax over n (wave reductions)
  float sim;
  {
    const float* mrow = mem + ((size_t)b*NN + t)*NWD;
    float dot = 0.f, n2 = 0.f;
    for (int d0=0; d0<64; d0+=4){
      float4 q = *(const float4*)(mrow + d0);
      dot += wkL[d0]*q.x + wkL[d0+1]*q.y + wkL[d0+2]*q.z + wkL[d0+3]*q.w;
      n2  += q.x*q.x + q.y*q.y + q.z*q.z + q.w*q.w;
    }
    sim = scal[6]*dot/(scal[7]*sqrtf(n2) + EPSc);
  }
  {
    float m_ = sim;
    #pragma unroll
    for (int off=32; off>0; off>>=1) m_ = fmaxf(m_, __shfl_xor(m_, off));
    if (l == 0) wred[w] = m_;
  }
  __syncthreads();
  float mx = fmaxf(fmaxf(wred[0],wred[1]), fmaxf(wred[2],wred[3]));
  float e = expf(sim - mx);
  {
    float s_ = e;
    #pragma unroll
    for (int off=32; off>0; off>>=1) s_ += __shfl_xor(s_, off);
    if (l == 0) wred[4+w] = s_;
  }
  __syncthreads();
  float content = e / (wred[4]+wred[5]+wred[6]+wred[7]);

  // 5. allocation: bitonic sort (in-wave shuffles; LDS only for j>=64), shuffle scan
  float key = EPSc + (1.f-EPSc)*us;
  int idx = t;
  SSTAGE(1,2)
  SSTAGE(2,4)  SSTAGE(1,4)
  SSTAGE(4,8)  SSTAGE(2,8)  SSTAGE(1,8)
  SSTAGE(8,16) SSTAGE(4,16) SSTAGE(2,16) SSTAGE(1,16)
  SSTAGE(16,32) SSTAGE(8,32) SSTAGE(4,32) SSTAGE(2,32) SSTAGE(1,32)
  SSTAGE(32,64) SSTAGE(16,64) SSTAGE(8,64) SSTAGE(4,64) SSTAGE(2,64) SSTAGE(1,64)
  LSTAGE(64,128)
  SSTAGE(32,128) SSTAGE(16,128) SSTAGE(8,128) SSTAGE(4,128) SSTAGE(2,128) SSTAGE(1,128)
  LSTAGE(128,256)
  LSTAGE(64,256)
  SSTAGE(32,256) SSTAGE(16,256) SSTAGE(8,256) SSTAGE(4,256) SSTAGE(2,256) SSTAGE(1,256)

  // inclusive cumprod: in-wave shuffle scan + cross-wave totals
  float v = key;
  #pragma unroll
  for (int off=1; off<64; off<<=1){
    float u = __shfl_up(v, off);
    if (l >= off) v *= u;
  }
  if (l == 63) wred[8+w] = v;
  __syncthreads();
  float pre = 1.f;
  #pragma unroll
  for (int q=0; q<3; q++) if (q < w) pre *= wred[8+q];
  float exv = __shfl_up(v, 1);
  if (l == 0) exv = 1.f;
  float excl = exv * pre;
  float s_alloc = (1.f - key) * excl;
  salloc[idx] = s_alloc;   // scatter back to original index
  __syncthreads();
  float alloc = salloc[t];

  // 6. write weights + precedence
  float ag = scal[4], wg = scal[5];
  float ww = wg*(ag*alloc + (1.f-ag)*content);
  pb[400 + t] = ww;
  out_ww[(size_t)b*NN + t] = ww;
  {
    float s_ = ww;
    #pragma unroll
    for (int off=32; off>0; off>>=1) s_ += __shfl_xor(s_, off);
    if (l == 0) wred[12+w] = s_;
  }
  __syncthreads();
  float wsum = wred[12]+wred[13]+wred[14]+wred[15];
  float prec = (1.f - wsum)*pprec[(size_t)b*NN + t] + ww;
  out_prec[(size_t)b*NN + t] = prec;
}

// ---------------- K4: fused link update + forward/backward matvecs (streaming) ----------------
// grid (1024 batch, 2 row-chunks), 256 threads. float4 stream of plink/out_link.
__global__ __launch_bounds__(256) void k4_link(
    const float* __restrict__ plink, const float* __restrict__ pprec,
    const float* __restrict__ prw_in, const float* __restrict__ params,
    float* __restrict__ out_link, float* __restrict__ fw, float* __restrict__ bwp)
{
  int b = blockIdx.x, cc = blockIdx.y, t = threadIdx.x;
  int w = t >> 6, l = t & 63;
  __shared__ float wwl[256], ppl[256], prwl[4*256];
  __shared__ v4f   bred[4][4][64];   // [wave][r][lane] -> 4 cols, 16 KB
  __shared__ float fwbuf[4*128];     // [wave][r*32+k]
  const float* pb = params + (size_t)b*672;
  wwl[t] = pb[400 + t];
  ppl[t] = pprec[(size_t)b*NN + t];
  #pragma unroll
  for (int r=0;r<4;r++) prwl[r*256 + t] = prw_in[((size_t)b*NR + r)*NN + t];
  __syncthreads();

  // per-lane column-constant registers (cols 4l..4l+3)
  v4f wwj = *(const v4f*)&wwl[4*l];
  v4f ppj = *(const v4f*)&ppl[4*l];
  v4f pr0 = *(const v4f*)&prwl[0*256 + 4*l];
  v4f pr1 = *(const v4f*)&prwl[1*256 + 4*l];
  v4f pr2 = *(const v4f*)&prwl[2*256 + 4*l];
  v4f pr3 = *(const v4f*)&prwl[3*256 + 4*l];

  v4f bacc0 = {0.f,0.f,0.f,0.f}, bacc1 = bacc0, bacc2 = bacc0, bacc3 = bacc0;

  int i0 = cc*128 + w*32;                      // this wave's 32-row strip
  const v4f* plrow = (const v4f*)(plink + ((size_t)b*NN + i0)*NN) + l;
  float*     olbase = out_link + ((size_t)b*NN + i0)*NN + 4*l;

  for (int k=0; k<32; k++){
    int i = i0 + k;
    v4f pl = plrow[(size_t)k*64];
    float wwi = wwl[i];                         // wave-uniform LDS broadcasts
    float c1  = 1.f - wwi;
    float pi0 = prwl[0*256+i], pi1 = prwl[1*256+i],
          pi2 = prwl[2*256+i], pi3 = prwl[3*256+i];
    v4f lv = (c1 - wwj)*pl + wwi*ppj;
    if (l == (i>>2)) lv[i&3] = 0.f;             // zero diagonal before matvecs
    __builtin_nontemporal_store(lv, (v4f*)(olbase + (size_t)k*NN));

    // forward partials (reduce over j within wave) + backward accumulators
    v4f f0 = pr0*lv, f1 = pr1*lv, f2 = pr2*lv, f3 = pr3*lv;
    float s0 = f0.x+f0.y+f0.z+f0.w;
    float s1 = f1.x+f1.y+f1.z+f1.w;
    float s2 = f2.x+f2.y+f2.z+f2.w;
    float s3 = f3.x+f3.y+f3.z+f3.w;
    bacc0 += pi0*lv; bacc1 += pi1*lv; bacc2 += pi2*lv; bacc3 += pi3*lv;

    // packed butterfly: 2 steps on all four, select by lane&3, 4 more steps
    s0 += __shfl_xor(s0,1); s0 += __shfl_xor(s0,2);
    s1 += __shfl_xor(s1,1); s1 += __shfl_xor(s1,2);
    s2 += __shfl_xor(s2,1); s2 += __shfl_xor(s2,2);
    s3 += __shfl_xor(s3,1); s3 += __shfl_xor(s3,2);
    float v = (l&1) ? ((l&2)? s3 : s1) : ((l&2)? s2 : s0);
    v += __shfl_xor(v,4); v += __shfl_xor(v,8);
    v += __shfl_xor(v,16); v += __shfl_xor(v,32);
    if (l < 4) fwbuf[w*128 + l*32 + k] = v;     // lane r holds fw[r][i]
  }

  bred[w][0][l] = bacc0;
  bred[w][1][l] = bacc1;
  bred[w][2][l] = bacc2;
  bred[w][3][l] = bacc3;
  __syncthreads();

  // combine backward across waves -> chunk partial; write fw coalesced
  {
    int r = t >> 6, l2 = t & 63;
    v4f a = bred[0][r][l2], b4 = bred[1][r][l2],
        c4 = bred[2][r][l2], d4 = bred[3][r][l2];
    v4f s = a + b4 + c4 + d4;
    *(v4f*)&bwp[(((size_t)cc*NB + b)*NR + r)*NN + 4*l2] = s;
    #pragma unroll
    for (int e=0;e<2;e++){
      int idx = t + e*256;
      int rr = idx >> 7, j = idx & 127;
      fw[((size_t)b*NR + rr)*NN + cc*128 + j] = fwbuf[(j>>5)*128 + rr*32 + (j&31)];
    }
  }
}

// ---------------- K5: memory update, read content/weights/words ----------------
// grid 1024 (batch), 256 threads
__global__ __launch_bounds__(256) void k5_read(
    const float* __restrict__ mem, const float* __restrict__ params,
    const float* __restrict__ fw, const float* __restrict__ bwp,
    float* __restrict__ out_rwords, float* __restrict__ out_mem, float* __restrict__ out_rweights)
{
  int b = blockIdx.x, t = threadIdx.x;
  __shared__ ush   memn[256*66];   // bf16 copy of new memory (read_words only)
  __shared__ float wvl[64], erl[64], rkl[256];
  __shared__ float siml[4*260];
  __shared__ float rwl[4*260];
  __shared__ float scal[32]; // kn[4]@0, M[4]@4, S[4]@8, rs[4]@12, mode[12]@16
  const float* pb = params + (size_t)b*672;
  if (t < 64){ wvl[t] = pb[t]; erl[t] = pb[64+t]; }
  rkl[t] = pb[128 + t];
  if (t < 4)  scal[12+t] = pb[384+t];
  if (t < 12) scal[16+t] = pb[388+t];
  __syncthreads();
  if (t < 4){
    float s = 0.f;
    for (int d=0;d<64;d++){ float v = rkl[t*64+d]; s += v*v; }
    scal[t] = sqrtf(s);
  }
  __syncthreads();

  // phase 1: memory erase/write; dots with read keys; row norms
  float wwn = pb[400 + t];
  const float* mrow = mem + ((size_t)b*NN + t)*NWD;
  float* orow = out_mem + ((size_t)b*NN + t)*NWD;
  float n2=0.f, dot0=0.f, dot1=0.f, dot2=0.f, dot3=0.f;
  for (int d0=0; d0<64; d0+=4){
    float4 q = *(const float4*)(mrow + d0);
    float4 qo;
    float* qi = (float*)&q;
    float* po = (float*)&qo;
    #pragma unroll
    for (int k=0;k<4;k++){
      int d = d0+k;
      float m = qi[k];
      float nv = m*(1.f - wwn*erl[d]) + wwn*wvl[d];
      po[k] = nv;
      n2 += nv*nv;
      dot0 += rkl[0*64+d]*nv;
      dot1 += rkl[1*64+d]*nv;
      dot2 += rkl[2*64+d]*nv;
      dot3 += rkl[3*64+d]*nv;
    }
    // packed bf16 LDS writes (2 dwords instead of 4 u16 stores)
    unsigned int p01 = (unsigned int)f2b(po[0]) | ((unsigned int)f2b(po[1]) << 16);
    unsigned int p23 = (unsigned int)f2b(po[2]) | ((unsigned int)f2b(po[3]) << 16);
    *(unsigned int*)&memn[t*66 + d0]     = p01;
    *(unsigned int*)&memn[t*66 + d0 + 2] = p23;
    *(float4*)(orow + d0) = qo;
  }
  float sn = sqrtf(n2);
  siml[0*260+t] = scal[12]*dot0/(scal[0]*sn + EPSc);
  siml[1*260+t] = scal[13]*dot1/(scal[1]*sn + EPSc);
  siml[2*260+t] = scal[14]*dot2/(scal[2]*sn + EPSc);
  siml[3*260+t] = scal[15]*dot3/(scal[3]*sn + EPSc);
  __syncthreads();

  // phase 2: softmax over n per r (wave rr handles r=rr)
  int rr = t >> 6, lane = t & 63;
  {
    float m1 = -1e30f;
    #pragma unroll
    for (int q2=0;q2<4;q2++) m1 = fmaxf(m1, siml[rr*260 + q2*64 + lane]);
    #pragma unroll
    for (int off=32; off>0; off>>=1) m1 = fmaxf(m1, __shfl_xor(m1, off));
    float s1 = 0.f;
    #pragma unroll
    for (int q2=0;q2<4;q2++) s1 += expf(siml[rr*260 + q2*64 + lane] - m1);
    #pragma unroll
    for (int off=32; off>0; off>>=1) s1 += __shfl_xor(s1, off);
    if (lane == 0){ scal[4+rr] = m1; scal[8+rr] = s1; }
  }
  __syncthreads();

  // phase 3: read weights = cm*content + fm*forward + bm*backward (bw = sum of 2 chunk partials)
  #pragma unroll
  for (int r=0;r<4;r++){
    float c = expf(siml[r*260+t] - scal[4+r]) / scal[8+r];
    float fwv = fw[((size_t)b*NR + r)*NN + t];
    float bwv = bwp[((size_t)b*NR + r)*NN + t]
              + bwp[((size_t)(NB + b)*NR + r)*NN + t];
    float rwv = scal[16+3*r+2]*c + scal[16+3*r+1]*fwv + scal[16+3*r+0]*bwv;
    rwl[r*260 + t] = rwv;
    out_rweights[((size_t)b*NR + r)*NN + t] = rwv;
  }
  __syncthreads();

  // phase 4: read words = rw @ new memory (wave rr, lane = d)
  {
    float acc = 0.f;
    for (int n=0;n<256;n++) acc += rwl[rr*260 + n]*b2f(memn[n*66 + lane]);
    out_rwords[((size_t)b*NR + rr)*NWD + lane] = acc;
  }
}

extern "C" void kernel_launch(void* const* d_in, const int* in_sizes, int n_in,
                              void* d_out, int out_size, void* d_ws, size_t ws_size,
                              hipStream_t stream) {
  const float* ctrl   = (const float*)d_in[0];
  const float* mem    = (const float*)d_in[1];
  const float* prw    = (const float*)d_in[2];
  const float* pww    = (const float*)d_in[3];
  const float* plink  = (const float*)d_in[4];
  const float* pprec  = (const float*)d_in[5];
  const float* pusage = (const float*)d_in[6];
  Ptrs P;
  for (int i=0;i<10;i++){
    P.W[i]  = (const float*)d_in[7 + 2*i];
    P.Bv[i] = (const float*)d_in[8 + 2*i];
  }
  float* ws = (float*)d_ws;
  float* part   = ws + WS_PART;
  float* params = ws + WS_PARAMS;
  float* fw     = ws + WS_FW;

  float* o = (float*)d_out;
  float* out_rwords   = o + OFF_RWORDS;
  float* out_mem      = o + OFF_MEM;
  float* out_rweights = o + OFF_RWEIGHTS;
  float* out_ww       = o + OFF_WW;
  float* out_link     = o + OFF_LINK;
  float* out_prec     = o + OFF_PREC;
  float* out_usage    = o + OFF_USAGE;

  k1_gemm<<<dim3(128,4), 256, 0, stream>>>(ctrl, P, part);
  k2_gates<<<NB, 256, 0, stream>>>(part, P, mem, prw, pww, pprec, pusage,
                                   params, out_ww, out_prec, out_usage);
  // k4 reuses `part` (k2 is done with it) for backward chunk partials: 2*1024*4*256 floats
  k4_link<<<dim3(NB,2), 256, 0, stream>>>(plink, pprec, prw, params, out_link, fw, part);
  k5_read<<<NB, 256, 0, stream>>>(mem, params, fw, part,
                                  out_rwords, out_mem, out_rweights);
}